// Round 9
// baseline (688.824 us; speedup 1.0000x reference)
//
#include <hip/hip_runtime.h>

typedef unsigned short u16;
typedef unsigned int u32;
typedef __attribute__((ext_vector_type(8))) short bf16x8;
typedef __attribute__((ext_vector_type(4))) float f32x4;
typedef __attribute__((ext_vector_type(16))) float f32x16;

#define TR 261888           // total anchor rows per batch image
#define LOGITS_OFF 0
#define PROBS_OFF  1047552  // 2*TR*2
#define DELTAS_OFF 2095104  // 2*(2*TR*2)

#define W3P_ELEMS (72 * 512 * 32)
#define W18P_ELEMS (32 * 512)
#define FLAG_OFF_BYTES ((W3P_ELEMS + W18P_ELEMS) * 2)   // 2,392,064

__device__ __forceinline__ float b2f(u16 u) {
    union { u32 i; float f; } v; v.i = ((u32)u) << 16; return v.f;
}
__device__ __forceinline__ u16 f2b(float f) {
    union { float f; u32 i; } v; v.f = f;
    u32 x = v.i;
    return (u16)((x + 0x7fffu + ((x >> 16) & 1u)) >> 16);
}
__device__ __forceinline__ float ldmix(const void* p, int i, bool isb16) {
    return isb16 ? b2f(((const u16*)p)[i]) : ((const float*)p)[i];
}

// Sh layout (GEMM2 staging): 64 px x 512 ch, stride 512, XOR swizzle.
// (verbatim from the harness-verified fused kernel)
__device__ __forceinline__ int sh_idx(int px, int c) {
    return px * 512 + (c ^ ((px & 3) * 8));
}

// ---------------------------------------------------------------------------
// Detect input dtype.
// ---------------------------------------------------------------------------
__global__ void detect_kernel(const u16* __restrict__ f0, int* __restrict__ flag) {
    int lane = threadIdx.x;          // 64 threads
    u16 v = f0[lane * 2];            // even u16 index
    int e = (v >> 7) & 0xFF;
    bool plausible = (e >= 90) && (e <= 140);
    unsigned long long m = __ballot(plausible);
    if (lane == 0) *flag = (__popcll(m) >= 48) ? 1 : 0;   // 1 = bf16, 0 = f32
}

// ---------------------------------------------------------------------------
// Repack: w_shared [2304,512] -> W3p[72][512][32] bf16
//   w_cls[512,6] + w_delta[512,12] -> W18p[32][512] bf16 (rows 18..31 = 0)
// ---------------------------------------------------------------------------
__global__ void repack_kernel(const void* __restrict__ w3,
                              const void* __restrict__ wcls,
                              const void* __restrict__ wdelta,
                              u16* __restrict__ W3p, u16* __restrict__ W18p,
                              const int* __restrict__ flag) {
    const bool isb16 = (*flag != 0);
    int tid = blockIdx.x * 256 + threadIdx.x;
    if (tid < W3P_ELEMS) {
        int k = tid & 31;
        int n = (tid >> 5) & 511;
        int c = tid >> 14;
        int K = c * 32 + k;          // global k index 0..2303
        float v = ldmix(w3, K * 512 + n, isb16);
        W3p[tid] = f2b(v);
    } else if (tid < W3P_ELEMS + W18P_ELEMS) {
        int t = tid - W3P_ELEMS;
        int k = t & 511;
        int j = t >> 9;
        float v = 0.f;
        if (j < 6)       v = ldmix(wcls, k * 6 + j, isb16);
        else if (j < 18) v = ldmix(wdelta, k * 12 + (j - 6), isb16);
        W18p[t] = f2b(v);
    }
}

// ---------------------------------------------------------------------------
// Fused RPN head, 32x32x16 MFMA, full 512-ch blocks (no N-split).
// One block = one 8x8 pixel tile; 4 waves, each 64px x 128ch (2M x 4N tiles).
// LDS A-traffic per tile is HALVED vs the nhalf-split version (no duplicate
// halo reads), W-L2 traffic unchanged (waves read disjoint W columns).
// Halo swizzle is 4-bit: slot = cg ^ ((p&7) | ((row&1)<<3)) -> the 32-lane
// A-fragment read (4 rows x 8 cols) is exactly 2-way per bank (free, m136).
// ---------------------------------------------------------------------------
__global__ __launch_bounds__(256, 2) void rpn_main(
    const void* __restrict__ f0, const void* __restrict__ f1,
    const void* __restrict__ f2, const void* __restrict__ f3,
    const void* __restrict__ f4,
    const void* __restrict__ bsh, const void* __restrict__ bcls,
    const void* __restrict__ bdelta,
    const u16* __restrict__ W3p, const u16* __restrict__ W18p,
    void* __restrict__ out, const int* __restrict__ flag)
{
    __shared__ u16 SMEM[32768];   // 65,536 B: halo (51.2 KB) then Sh (64 KB)

    const bool isb16 = (*flag != 0);

    const int tid  = threadIdx.x;
    const int wv   = tid >> 6;
    const int lane = tid & 63;
    const int l32  = lane & 31;
    const int hi   = lane >> 5;          // 0/1: k-quarter selector for 32x32x16
    const int quad = lane >> 4;          // for GEMM2 (16x16)
    const int l16  = lane & 15;

    // branchless level lookup (uniform per block)
    const int bid = blockIdx.x;
    const int lvl = (bid >= 2048) + (bid >= 2560) + (bid >= 2688) + (bid >= 2720);
    const int tileBase = (lvl == 0) ? 0 : (lvl == 1) ? 2048 : (lvl == 2) ? 2560
                        : (lvl == 3) ? 2688 : 2720;
    const int logS   = 8 - lvl;
    const int S      = 1 << logS;
    const int rowOff = (lvl == 0) ? 0 : (lvl == 1) ? 196608 : (lvl == 2) ? 245760
                      : (lvl == 3) ? 258048 : 261120;
    const void* feat = (lvl == 0) ? f0 : (lvl == 1) ? f1 : (lvl == 2) ? f2
                      : (lvl == 3) ? f3 : f4;
    const int tile = bid - tileBase;

    const int logT = logS - 3;
    const int b    = tile >> (2 * logT);
    const int t2   = tile & ((1 << (2 * logT)) - 1);
    const int th   = t2 >> logT;
    const int tw   = t2 & ((1 << logT) - 1);
    const int h0   = th << 3, w0 = tw << 3;

    // ---------------- stage 10x10x256 halo -> LDS (bf16, 4-bit swizzle) -----
    for (int g = tid; g < 3200; g += 256) {
        const int p  = g >> 5;
        const int cg = g & 31;
        const int hh = p / 10;
        const int ww = p - hh * 10;
        const int ih = h0 + hh - 1;
        const int iw = w0 + ww - 1;
        uint4 v; v.x = 0u; v.y = 0u; v.z = 0u; v.w = 0u;
        if (ih >= 0 && ih < S && iw >= 0 && iw < S) {
            const size_t gaddr = ((size_t)((b * S + ih) * S + iw)) * 256 + cg * 8;
            if (isb16) {
                v = *(const uint4*)((const u16*)feat + gaddr);
            } else {
                const float* fp = (const float*)feat + gaddr;
                float4 x = *(const float4*)fp;
                float4 y = *(const float4*)(fp + 4);
                v.x = (u32)f2b(x.x) | ((u32)f2b(x.y) << 16);
                v.y = (u32)f2b(x.z) | ((u32)f2b(x.w) << 16);
                v.z = (u32)f2b(y.x) | ((u32)f2b(y.y) << 16);
                v.w = (u32)f2b(y.z) | ((u32)f2b(y.w) << 16);
            }
        }
        const int sw = (p & 7) | ((hh & 1) << 3);
        *(uint4*)&SMEM[p * 256 + ((cg ^ sw) << 3)] = v;
    }
    __syncthreads();

    f32x16 acc[2][4];
#pragma unroll
    for (int mt = 0; mt < 2; ++mt)
#pragma unroll
        for (int nt = 0; nt < 4; ++nt)
#pragma unroll
            for (int r = 0; r < 16; ++r) acc[mt][nt][r] = 0.f;

    // lane's base halo pixel for Mt=0, center tap
    const int pLane32 = ((l32 >> 3) + 1) * 10 + (l32 & 7) + 1;
    // wave owns ch [wv*128, wv*128+128): 4 N-tiles of 32
    const u16* __restrict__ Wp = W3p + (u32)(wv * 128 + l32) * 32 + (u32)hi * 8;

    // W frags for current chunk: wq[nt*2+ks]
    bf16x8 wq[8];
#pragma unroll
    for (int i = 0; i < 8; ++i)
        wq[i] = *(const bf16x8*)&Wp[(i >> 1) * 1024 + (i & 1) * 16];

    // one chunk: 4 ds_read A-frags, 16 MFMA 32x32x16, inline W refill
#define CHUNK(CC)                                                             \
    {                                                                         \
        const int kc = tap * 8 + (CC);                                        \
        const int kcn = (kc + 1 < 72) ? (kc + 1) : kc;                        \
        bf16x8 af[2][2];                                                      \
        _Pragma("unroll")                                                     \
        for (int mt = 0; mt < 2; ++mt)                                        \
            _Pragma("unroll")                                                 \
            for (int ks = 0; ks < 2; ++ks)                                    \
                af[mt][ks] = *(const bf16x8*)                                 \
                    &SMEM[sbase[mt] +                                         \
                          ((((CC) * 4 + ks * 2 + hi) ^ sx[mt]) << 3)];        \
        __builtin_amdgcn_s_setprio(1);                                        \
        _Pragma("unroll")                                                     \
        for (int ks = 0; ks < 2; ++ks)                                        \
            _Pragma("unroll")                                                 \
            for (int nt = 0; nt < 4; ++nt) {                                  \
                acc[0][nt] = __builtin_amdgcn_mfma_f32_32x32x16_bf16(         \
                    af[0][ks], wq[nt * 2 + ks], acc[0][nt], 0, 0, 0);         \
                acc[1][nt] = __builtin_amdgcn_mfma_f32_32x32x16_bf16(         \
                    af[1][ks], wq[nt * 2 + ks], acc[1][nt], 0, 0, 0);         \
                wq[nt * 2 + ks] = *(const bf16x8*)                            \
                    &Wp[(size_t)kcn * 16384 + nt * 1024 + ks * 16];           \
            }                                                                 \
        __builtin_amdgcn_s_setprio(0);                                        \
    }

    // ---------------- K loop: 9 taps x 8 chunks of 32 ch, barrier-free ------
    for (int tap = 0; tap < 9; ++tap) {
        const int dh = tap / 3 - 1, dw = tap % 3 - 1;
        const int rowpar = ((l32 >> 3) + 1 + dh) & 1;   // mt*4 is even
        int sbase[2], sx[2];
#pragma unroll
        for (int mt = 0; mt < 2; ++mt) {
            const int p = pLane32 + (mt * 4 + dh) * 10 + dw;
            sbase[mt] = p * 256;
            sx[mt]    = (p & 7) | (rowpar << 3);
        }
        CHUNK(0) CHUNK(1) CHUNK(2) CHUNK(3)
        CHUNK(4) CHUNK(5) CHUNK(6) CHUNK(7)
    }
#undef CHUNK

    __syncthreads();   // all waves done reading halo before Sh overwrites it

    // ------- epilogue: bias+relu -> Sh (64px x 512ch, sh_idx swizzle) -------
    // 32x32 D-layout: n = wv*128 + nt*32 + l32,
    //                 px = mt*32 + (r&3) + 8*(r>>2) + 4*hi
#pragma unroll
    for (int nt = 0; nt < 4; ++nt) {
        const int n = wv * 128 + nt * 32 + l32;
        const float bn = ldmix(bsh, n, isb16);
#pragma unroll
        for (int mt = 0; mt < 2; ++mt) {
#pragma unroll
            for (int r = 0; r < 16; ++r) {
                const int px = mt * 32 + (r & 3) + 8 * (r >> 2) + 4 * hi;
                float vv = acc[mt][nt][r] + bn;
                vv = vv > 0.f ? vv : 0.f;
                SMEM[sh_idx(px, n)] = f2b(vv);
            }
        }
    }
    __syncthreads();

    // ---------------- GEMM2: out18 = W18 (A, m=j) x Sh^T (B, n=px) ----------
    const f32x4 zf = {0.f, 0.f, 0.f, 0.f};
    f32x4 a2[2];
    a2[0] = zf; a2[1] = zf;
#pragma unroll
    for (int jt = 0; jt < 2; ++jt) {
#pragma unroll
        for (int ks = 0; ks < 16; ++ks) {
            bf16x8 wa = *(const bf16x8*)&W18p[(jt * 16 + l16) * 512 + ks * 32 + quad * 8];
            bf16x8 sb = *(const bf16x8*)&SMEM[sh_idx(wv * 16 + l16, ks * 32 + quad * 8)];
            a2[jt] = __builtin_amdgcn_mfma_f32_16x16x32_bf16(wa, sb, a2[jt], 0, 0, 0);
        }
    }

    // ---------------- outputs ----------------
    const int px2  = wv * 16 + l16;                // this lane's in-tile pixel
    const int Pimg = (h0 + (px2 >> 3)) * S + (w0 + (px2 & 7));
    const size_t rowBase = (size_t)b * TR + rowOff + (size_t)Pimg * 3;
    u16*   o16 = (u16*)out;
    float* o32 = (float*)out;
    auto storeOut = [&](size_t idx, float v) {
        if (isb16) o16[idx] = f2b(v); else o32[idx] = v;
    };

    // deltas: j in [6,18)
#pragma unroll
    for (int jt = 0; jt < 2; ++jt) {
#pragma unroll
        for (int r = 0; r < 4; ++r) {
            const int j = jt * 16 + quad * 4 + r;
            if (j >= 6 && j < 18) {
                const int dj = j - 6;
                float vv = a2[jt][r] + ldmix(bdelta, dj, isb16);
                storeOut(DELTAS_OFF + (rowBase + (dj >> 2)) * 4 + (dj & 3), vv);
            }
        }
    }
    // cls logits + softmax: pairs are within-lane
    auto writePair = [&](int r, float v0, float v1) {
        const float bl0 = ldmix(bcls, 2 * r, isb16);
        const float bl1 = ldmix(bcls, 2 * r + 1, isb16);
        const float L0 = v0 + bl0, L1 = v1 + bl1;
        const size_t row = rowBase + r;
        storeOut(LOGITS_OFF + row * 2 + 0, L0);
        storeOut(LOGITS_OFF + row * 2 + 1, L1);
        const float m = fmaxf(L0, L1);
        const float e0 = __expf(L0 - m), e1 = __expf(L1 - m);
        const float inv = 1.0f / (e0 + e1);
        storeOut(PROBS_OFF + row * 2 + 0, e0 * inv);
        storeOut(PROBS_OFF + row * 2 + 1, e1 * inv);
    };
    if (quad == 0) {
        writePair(0, a2[0][0], a2[0][1]);
        writePair(1, a2[0][2], a2[0][3]);
    } else if (quad == 1) {
        writePair(2, a2[0][0], a2[0][1]);
    }
}

// ---------------------------------------------------------------------------
extern "C" void kernel_launch(void* const* d_in, const int* in_sizes, int n_in,
                              void* d_out, int out_size, void* d_ws, size_t ws_size,
                              hipStream_t stream) {
    const void* f0     = d_in[0];
    const void* f1     = d_in[1];
    const void* f2     = d_in[2];
    const void* f3     = d_in[3];
    const void* f4     = d_in[4];
    const void* w3     = d_in[5];
    const void* bsh    = d_in[6];
    const void* wcls   = d_in[7];
    const void* bcls   = d_in[8];
    const void* wdelta = d_in[9];
    const void* bdelta = d_in[10];

    u16* W3p  = (u16*)d_ws;
    u16* W18p = W3p + W3P_ELEMS;
    int* flag = (int*)((char*)d_ws + FLAG_OFF_BYTES);

    detect_kernel<<<1, 64, 0, stream>>>((const u16*)f0, flag);
    repack_kernel<<<4672, 256, 0, stream>>>(w3, wcls, wdelta, W3p, W18p, flag);
    rpn_main<<<2728, 256, 0, stream>>>(f0, f1, f2, f3, f4,
                                       bsh, bcls, bdelta, W3p, W18p,
                                       d_out, flag);
}